// Round 4
// baseline (159.891 us; speedup 1.0000x reference)
//
#include <hip/hip_runtime.h>

namespace {

constexpr int B = 16;
constexpr int C = 1024;
constexpr int BC = B * C;                          // 16384
constexpr long long BCC = (long long)B * C * C;    // 16777216
constexpr float EPS  = 1e-12f;
constexpr float TINY = 1e-9f;

typedef float vfloat4 __attribute__((ext_vector_type(4)));

// ---------------------------------------------------------------------------
// K0: per-(b,j) tables El=exp(l), Eu=exp(u), Em=exp(h), W=u-l, plus per-batch
// separable sums {SumEl, SumEu, P0=SumEm, P1=Sum Em*(1-h)}. One block per b.
// ---------------------------------------------------------------------------
__global__ __launch_bounds__(256) void k0_tables(
    const float* __restrict__ lower, const float* __restrict__ upper,
    float* __restrict__ El, float* __restrict__ Eu,
    float* __restrict__ Em, float* __restrict__ W,
    float* __restrict__ Bsum)
{
    const int b   = blockIdx.x;
    const int tid = threadIdx.x;
    const int base = b * C + tid * 4;

    const vfloat4 l4 = *reinterpret_cast<const vfloat4*>(lower + base);
    const vfloat4 u4 = *reinterpret_cast<const vfloat4*>(upper + base);

    vfloat4 el, eu, em, w;
    float s0 = 0.f, s1 = 0.f, s2 = 0.f, s3 = 0.f;
    #pragma unroll
    for (int k = 0; k < 4; ++k) {
        const float e_l = __expf(l4[k]);
        const float e_u = __expf(u4[k]);
        const float h   = 0.5f * (l4[k] + u4[k]);
        const float e_m = __expf(h);
        el[k] = e_l; eu[k] = e_u; em[k] = e_m; w[k] = u4[k] - l4[k];
        s0 += e_l; s1 += e_u; s2 += e_m; s3 += e_m * (1.0f - h);
    }
    *reinterpret_cast<vfloat4*>(El + base) = el;
    *reinterpret_cast<vfloat4*>(Eu + base) = eu;
    *reinterpret_cast<vfloat4*>(Em + base) = em;
    *reinterpret_cast<vfloat4*>(W  + base) = w;

    __shared__ float red[4][4];
    const int lane = tid & 63, wid = tid >> 6;
    float v[4] = {s0, s1, s2, s3};
    #pragma unroll
    for (int m = 0; m < 4; ++m) {
        #pragma unroll
        for (int o = 32; o > 0; o >>= 1) v[m] += __shfl_down(v[m], o);
        if (lane == 0) red[wid][m] = v[m];
    }
    __syncthreads();
    if (tid == 0) {
        #pragma unroll
        for (int m = 0; m < 4; ++m)
            Bsum[b * 4 + m] = red[0][m] + red[1][m] + red[2][m] + red[3][m];
    }
}

// ---------------------------------------------------------------------------
// K1: one block per row (b,i). Separable scalars in O(1) from Bsum; only the
// two non-separable sums (SA_u = sum a_u, T = sum a_u*l_j) are block-reduced.
// Writes the 4 small outputs + 8 per-row scalars for K2. No big stores.
// ---------------------------------------------------------------------------
__global__ __launch_bounds__(256) void k1_rows(
    const float* __restrict__ lower, const float* __restrict__ upper,
    const float* __restrict__ El, const float* __restrict__ Eu,
    const float* __restrict__ Em, const float* __restrict__ W,
    const float* __restrict__ Bsum,
    float* __restrict__ RS, float* __restrict__ out)
{
    const int row = blockIdx.x;
    const int b   = row >> 10;
    const int tid = threadIdx.x;

    const float l_i  = lower[row], u_i = upper[row];
    const float El_i = El[row], Eu_i = Eu[row], Em_i = Em[row], w_i = W[row];
    const float su = __builtin_amdgcn_rcpf(Eu_i);   // exp(-u_i)
    const float sl = __builtin_amdgcn_rcpf(El_i);   // exp(-l_i)
    const float sm = __builtin_amdgcn_rcpf(Em_i);   // exp(-h_i)

    const int base = b * C + tid * 4;
    const vfloat4 El4 = *reinterpret_cast<const vfloat4*>(El + base);
    const vfloat4 Eu4 = *reinterpret_cast<const vfloat4*>(Eu + base);
    const vfloat4 W4  = *reinterpret_cast<const vfloat4*>(W  + base);
    const vfloat4 l4  = *reinterpret_cast<const vfloat4*>(lower + base);

    float accA = 0.f, accT = 0.f;   // include diag; subtracted exactly below
    #pragma unroll
    for (int k = 0; k < 4; ++k) {
        const float eu = Eu4[k] * sl;
        const float el = El4[k] * su;
        const float denom = W4[k] + w_i;
        const float r = __builtin_amdgcn_rcpf(denom + EPS);
        float a = (eu - el) * r;
        a = (fabsf(denom) < TINY) ? eu : a;
        accA += a;
        accT += a * l4[k];
    }

    __shared__ float red[4][2];
    const int lane = tid & 63, wid = tid >> 6;
    #pragma unroll
    for (int o = 32; o > 0; o >>= 1) accA += __shfl_down(accA, o);
    #pragma unroll
    for (int o = 32; o > 0; o >>= 1) accT += __shfl_down(accT, o);
    if (lane == 0) { red[wid][0] = accA; red[wid][1] = accT; }
    __syncthreads();

    if (tid == 0) {
        const float A_all = red[0][0] + red[1][0] + red[2][0] + red[3][0];
        const float T_all = red[0][1] + red[1][1] + red[2][1] + red[3][1];

        // diagonal term, bit-identical to what the loop accumulated at j==i
        const float eu_d = Eu_i * sl;
        const float el_d = El_i * su;
        const float den_d = w_i + w_i;
        const float r_d = __builtin_amdgcn_rcpf(den_d + EPS);
        float a_d = (eu_d - el_d) * r_d;
        a_d = (fabsf(den_d) < TINY) ? eu_d : a_d;
        const float SA_u = A_all - a_d;
        const float Tn   = T_all - a_d * l_i;

        const float SEl = Bsum[b * 4 + 0];
        const float SEu = Bsum[b * 4 + 1];
        const float P0  = Bsum[b * 4 + 2];
        const float P1  = Bsum[b * 4 + 3];

        const float S_l  = su * (SEl - El_i);
        const float S_u  = sl * (SEu - Eu_i);
        const float SA_l = sm * (P0  - Em_i);
        const float h_i  = 0.5f * (l_i + u_i);
        const float SB_l = sm * fmaf(h_i, P0, P1) - 1.0f;
        const float SB_u = S_l - Tn + u_i * SA_u;

        const float g_l = 1.0f / (1.0f + S_l);
        const float g_u = 1.0f / (1.0f + S_u);
        const float dg  = S_u - S_l;
        float m_u = (g_u - g_l) / (dg + EPS);
        m_u = (fabsf(dg) < TINY) ? (-g_u * g_u) : m_u;
        const float c_u = g_l - m_u * S_l;
        const float m_l = -g_u * g_u;
        const float c_l = g_u - m_l * S_u;

        out[row]                         = fminf(fmaxf(g_u, 0.0f), 1.0f);
        out[BC + row]                    = fminf(fmaxf(g_l, 0.0f), 1.0f);
        out[2 * BC + 2 * BCC + row]      = fmaf(m_l, SB_l, c_l);
        out[2 * BC + 2 * BCC + BC + row] = fmaf(m_u, SB_u, c_u);

        vfloat4 rs0, rs1;
        rs0[0] = m_u;  rs0[1] = su;        rs0[2] = sl;         rs0[3] = w_i;
        rs1[0] = -m_u * SA_u;  rs1[1] = m_l * sm;  rs1[2] = -m_l * SA_l;  rs1[3] = 0.f;
        *reinterpret_cast<vfloat4*>(RS + (long long)row * 8)     = rs0;
        *reinterpret_cast<vfloat4*>(RS + (long long)row * 8 + 4) = rs1;
    }
}

// ---------------------------------------------------------------------------
// K2: pure streaming writer for the two (B,C,C) coef arrays. No barriers, no
// reductions. 4 rows per block, j-tables held in registers across the rows.
// ---------------------------------------------------------------------------
__global__ __launch_bounds__(256) void k2_stream(
    const float* __restrict__ El, const float* __restrict__ Eu,
    const float* __restrict__ Em, const float* __restrict__ W,
    const float* __restrict__ RS, float* __restrict__ out)
{
    const int blk = blockIdx.x;            // 4096
    const int b   = blk >> 8;
    const int ig  = blk & 255;
    const int tid = threadIdx.x;
    const int j0  = tid * 4;
    const int tbase = b * C + j0;

    const vfloat4 El4 = *reinterpret_cast<const vfloat4*>(El + tbase);
    const vfloat4 Eu4 = *reinterpret_cast<const vfloat4*>(Eu + tbase);
    const vfloat4 Em4 = *reinterpret_cast<const vfloat4*>(Em + tbase);
    const vfloat4 W4  = *reinterpret_cast<const vfloat4*>(W  + tbase);

    float* __restrict__ lower_base = out + 2 * BC;
    float* __restrict__ upper_base = out + 2 * BC + BCC;

    #pragma unroll
    for (int r = 0; r < 4; ++r) {
        const int i   = ig * 4 + r;
        const int row = b * C + i;
        const vfloat4 rs0 = *reinterpret_cast<const vfloat4*>(RS + (long long)row * 8);
        const vfloat4 rs1 = *reinterpret_cast<const vfloat4*>(RS + (long long)row * 8 + 4);
        const float m_u = rs0[0], su = rs0[1], sl = rs0[2], w_i = rs0[3];
        const float DiagU = rs1[0], MlE = rs1[1], DiagL = rs1[2];

        vfloat4 up, lo;
        #pragma unroll
        for (int k = 0; k < 4; ++k) {
            const float eu = Eu4[k] * sl;
            const float el = El4[k] * su;
            const float denom = W4[k] + w_i;
            const float rc = __builtin_amdgcn_rcpf(denom + EPS);
            float a = (eu - el) * rc;
            a = (fabsf(denom) < TINY) ? eu : a;
            up[k] = m_u * a;
            lo[k] = MlE * Em4[k];
            if (j0 + k == i) { up[k] = DiagU; lo[k] = DiagL; }
        }
        const long long off = (long long)row * C + j0;
        __builtin_nontemporal_store(lo, reinterpret_cast<vfloat4*>(lower_base + off));
        __builtin_nontemporal_store(up, reinterpret_cast<vfloat4*>(upper_base + off));
    }
}

} // namespace

extern "C" void kernel_launch(void* const* d_in, const int* in_sizes, int n_in,
                              void* d_out, int out_size, void* d_ws, size_t ws_size,
                              hipStream_t stream) {
    const float* lower = (const float*)d_in[0];
    const float* upper = (const float*)d_in[1];
    float* out = (float*)d_out;

    float* El   = (float*)d_ws;         // BC
    float* Eu   = El + BC;              // BC
    float* Em   = Eu + BC;              // BC
    float* W    = Em + BC;              // BC
    float* Bsum = W + BC;               // 16*4
    float* RS   = Bsum + 64;            // BC*8

    k0_tables<<<dim3(B), dim3(256), 0, stream>>>(lower, upper, El, Eu, Em, W, Bsum);
    k1_rows<<<dim3(BC), dim3(256), 0, stream>>>(lower, upper, El, Eu, Em, W, Bsum, RS, out);
    k2_stream<<<dim3(4096), dim3(256), 0, stream>>>(El, Eu, Em, W, RS, out);
}